// Round 1
// baseline (940.886 us; speedup 1.0000x reference)
//
#include <hip/hip_runtime.h>

// ---------------------------------------------------------------------------
// LabelCrossAttentionDE: out[b,c] = LN(softmax(Q K^T) V) . out_w + out_b
// B=2, S=4096, C=8000, D=768, SCALE=1 (fp16 MFMA path, fp32 accumulate)
// ---------------------------------------------------------------------------

typedef _Float16 half8  __attribute__((ext_vector_type(8)));
typedef _Float16 half4v __attribute__((ext_vector_type(4)));
typedef float    f32x4  __attribute__((ext_vector_type(4)));
typedef float    f32x16 __attribute__((ext_vector_type(16)));

#define L2E 1.44269504088896340736f

__device__ __forceinline__ void gld_lds16(_Float16* lds, const _Float16* g) {
  __builtin_amdgcn_global_load_lds(
      (const __attribute__((address_space(1))) unsigned int*)g,
      (__attribute__((address_space(3))) unsigned int*)lds, 16, 0, 0);
}

// ------------------------------ f32 -> f16 ---------------------------------
__global__ void cvt_kernel(const float* __restrict__ src, _Float16* __restrict__ dst, int n4) {
  int i = blockIdx.x * blockDim.x + threadIdx.x;
  if (i >= n4) return;
  float4 v = reinterpret_cast<const float4*>(src)[i];
  half4v h; h[0] = (_Float16)v.x; h[1] = (_Float16)v.y; h[2] = (_Float16)v.z; h[3] = (_Float16)v.w;
  reinterpret_cast<half4v*>(dst)[i] = h;
}

// ---------------- GEMM: C[M,N] f16 = A[M,768] @ Bt[N,768]^T (+bias[row]) ----
// 128x128 tile, BK=64, 4 waves (2x2), 16x16x32_f16, global_load_lds staging
// with pre-swizzled source (XOR slot^(row&7)) and swizzled ds_read_b128.
__global__ __launch_bounds__(256, 2) void gemm_nt_f16(
    const _Float16* __restrict__ A, const _Float16* __restrict__ Bt,
    _Float16* __restrict__ C, const float* __restrict__ bias, int M, int N)
{
  __shared__ __align__(16) _Float16 As[2][128 * 64];
  __shared__ __align__(16) _Float16 Bs[2][128 * 64];
  const int tid = threadIdx.x;
  const int lane = tid & 63, wid = tid >> 6;
  const int ntn = N >> 7;
  const int mtile = blockIdx.x / ntn, ntile = blockIdx.x - mtile * ntn;
  const int m0 = mtile << 7, n0 = ntile << 7;
  const int wm = wid >> 1, wn = wid & 1;

  f32x4 acc[4][4] = {};

  auto stage = [&](int buf, int kt) {
#pragma unroll
    for (int j = 0; j < 4; ++j) {
      int idx = (j << 8) + tid;
      int row = idx >> 3, slot = idx & 7;
      int gc = (kt << 6) + ((slot ^ (row & 7)) << 3);
      _Float16* ldsbase_a = &As[buf][(size_t)(((j << 8) + (wid << 6)) << 3)];
      _Float16* ldsbase_b = &Bs[buf][(size_t)(((j << 8) + (wid << 6)) << 3)];
      gld_lds16(ldsbase_a, &A[(size_t)(m0 + row) * 768 + gc]);
      gld_lds16(ldsbase_b, &Bt[(size_t)(n0 + row) * 768 + gc]);
    }
  };

  stage(0, 0);
  __syncthreads();

  for (int kt = 0; kt < 12; ++kt) {
    int cur = kt & 1;
    if (kt < 11) stage(cur ^ 1, kt + 1);
#pragma unroll
    for (int ks = 0; ks < 2; ++ks) {
      half8 a[4], b[4];
      int dloc = (ks << 5) + ((lane >> 4) << 3);
#pragma unroll
      for (int mi = 0; mi < 4; ++mi) {
        int row = (wm << 6) + (mi << 4) + (lane & 15);
        a[mi] = *reinterpret_cast<const half8*>(&As[cur][row * 64 + (dloc ^ ((row & 7) << 3))]);
      }
#pragma unroll
      for (int ni = 0; ni < 4; ++ni) {
        int row = (wn << 6) + (ni << 4) + (lane & 15);
        b[ni] = *reinterpret_cast<const half8*>(&Bs[cur][row * 64 + (dloc ^ ((row & 7) << 3))]);
      }
#pragma unroll
      for (int mi = 0; mi < 4; ++mi)
#pragma unroll
        for (int ni = 0; ni < 4; ++ni)
          acc[mi][ni] = __builtin_amdgcn_mfma_f32_16x16x32_f16(a[mi], b[ni], acc[mi][ni], 0, 0, 0);
    }
    __syncthreads();
  }

#pragma unroll
  for (int mi = 0; mi < 4; ++mi)
#pragma unroll
    for (int ni = 0; ni < 4; ++ni) {
      int col = n0 + (wn << 6) + (ni << 4) + (lane & 15);
#pragma unroll
      for (int r = 0; r < 4; ++r) {
        int row = m0 + (wm << 6) + (mi << 4) + ((lane >> 4) << 2) + r;
        float v = acc[mi][ni][r];
        if (bias) v += bias[row];
        C[(size_t)row * N + col] = (_Float16)v;
      }
    }
}

// --------------------------- fused attention -------------------------------
// Block: 8 waves, 64 c-rows, S in tiles of 256. Q (64x768 f16) in LDS.
// K fragments and V^T fragments read directly from global (L2/LLC resident).
// Online softmax cross-wave combine through LDS; LN + out_w dot fused epilogue.
__global__ __launch_bounds__(512, 2) void attn_kernel(
    const float* __restrict__ Qf, const _Float16* __restrict__ Kh,
    const _Float16* __restrict__ Vt,
    const float* __restrict__ gamma, const float* __restrict__ beta,
    const float* __restrict__ outw, const float* __restrict__ outb,
    float* __restrict__ out)
{
  __shared__ __align__(16) _Float16 Qs[64 * 768];   // 96 KB, XOR-swizzled
  __shared__ __align__(16) _Float16 Ps[64 * 256];   // 32 KB, XOR-swizzled
  __shared__ float redmax[8 * 64];
  __shared__ float redsum[8 * 64];
  __shared__ float mrow[64], lrow[64], rrow[64];
  __shared__ float gws[768];
  __shared__ float epi[64 * 24];
  __shared__ float scal[2];

  const int tid = threadIdx.x;
  const int lane = tid & 63;
  const int wid = tid >> 6;
  const int l31 = lane & 31;
  const int lh = lane >> 5;

  // bijective XCD swizzle for 250 blocks (q=31, r=2)
  int xcd = blockIdx.x & 7, idx8 = blockIdx.x >> 3;
  int f = (xcd < 2) ? xcd * 32 + idx8 : 64 + (xcd - 2) * 31 + idx8;
  const int bb = f / 125;
  const int ct = f - bb * 125;
  const int c0 = ct << 6;

  // ---- stage Q: fp32 -> fp16, swizzled into LDS ----
#pragma unroll
  for (int i = 0; i < 24; ++i) {
    int idx = tid + (i << 9);
    int row = idx / 192, c4 = idx - row * 192;
    float4 v = reinterpret_cast<const float4*>(Qf)[(size_t)(c0 + row) * 192 + c4];
    half4v h; h[0] = (_Float16)v.x; h[1] = (_Float16)v.y; h[2] = (_Float16)v.z; h[3] = (_Float16)v.w;
    *reinterpret_cast<half4v*>(&Qs[row * 768 + ((c4 << 2) ^ ((row & 7) << 3))]) = h;
  }
  for (int i = tid; i < 768; i += 512) gws[i] = gamma[i] * outw[i];
  if (tid < 64) { mrow[tid] = -1e30f; lrow[tid] = 0.f; }
  __syncthreads();
  if (tid < 64) {  // G = sum(gamma*w), BW = sum(beta*w)
    float g = 0.f, bw = 0.f;
#pragma unroll
    for (int j = 0; j < 12; ++j) { int d = tid + (j << 6); g += gws[d]; bw += beta[d] * outw[d]; }
#pragma unroll
    for (int m = 32; m; m >>= 1) { g += __shfl_xor(g, m); bw += __shfl_xor(bw, m); }
    if (tid == 0) { scal[0] = g; scal[1] = bw; }
  }

  f32x16 acc00 = {}, acc01 = {}, acc02 = {};  // y rows 0-31, 3 n-frags (96 cols)
  f32x16 acc10 = {}, acc11 = {}, acc12 = {};  // y rows 32-63

  const int n0w = wid * 96;
  const _Float16* qr0 = &Qs[l31 * 768];
  const _Float16* qr1 = &Qs[(32 + l31) * 768];
  const int qswz = (l31 & 7) << 3;
  const _Float16* kcol = Kh + (size_t)((bb << 12) + (wid << 5) + l31) * 768 + (lh << 3);
  const _Float16* vcol = Vt + (size_t)(n0w + l31) * 8192 + (bb << 12) + (lh << 3);

  for (int st = 0; st < 16; ++st) {
    const int s0 = st << 8;
    // ===================== QK^T (32x32x16, depth-3 prefetch) ===============
    f32x16 qk0 = {}, qk1 = {};
    const _Float16* kb = kcol + (size_t)s0 * 768;
    uint4 p0 = *reinterpret_cast<const uint4*>(kb);
    uint4 p1 = *reinterpret_cast<const uint4*>(kb + 16);
    uint4 p2 = *reinterpret_cast<const uint4*>(kb + 32);
#pragma unroll
    for (int k = 0; k < 48; ++k) {
      half8 bf = __builtin_bit_cast(half8, p0);
      p0 = p1; p1 = p2;
      if (k < 45) p2 = *reinterpret_cast<const uint4*>(kb + (k + 3) * 16);
      int del = (k << 4) + (lh << 3);
      half8 a0 = *reinterpret_cast<const half8*>(&qr0[del ^ qswz]);
      half8 a1 = *reinterpret_cast<const half8*>(&qr1[del ^ qswz]);
      qk0 = __builtin_amdgcn_mfma_f32_32x32x16_f16(a0, bf, qk0, 0, 0, 0);
      qk1 = __builtin_amdgcn_mfma_f32_32x32x16_f16(a1, bf, qk1, 0, 0, 0);
    }
    // ===================== online softmax ==================================
#pragma unroll
    for (int r = 0; r < 16; ++r) {
      float v0 = qk0[r], v1 = qk1[r];
#pragma unroll
      for (int m = 1; m <= 16; m <<= 1) {
        v0 = fmaxf(v0, __shfl_xor(v0, m));
        v1 = fmaxf(v1, __shfl_xor(v1, m));
      }
      if (l31 == 0) {
        int row = (r & 3) + ((r >> 2) << 3) + (lh << 2);
        redmax[(wid << 6) + row] = v0;
        redmax[(wid << 6) + 32 + row] = v1;
      }
    }
    __syncthreads();
    if (tid < 64) {
      float pm = redmax[tid];
#pragma unroll
      for (int w = 1; w < 8; ++w) pm = fmaxf(pm, redmax[(w << 6) + tid]);
      float mo = mrow[tid];
      float mn = fmaxf(mo, pm);
      mrow[tid] = mn;
      rrow[tid] = exp2f((mo - mn) * L2E);
    }
    __syncthreads();
    const int colP = (wid << 5) + l31;
#pragma unroll
    for (int r = 0; r < 16; ++r) {
      int row = (r & 3) + ((r >> 2) << 3) + (lh << 2);
      float pa = exp2f((qk0[r] - mrow[row]) * L2E);
      float pb = exp2f((qk1[r] - mrow[32 + row]) * L2E);
      int swz2 = (row & 7) << 3;
      Ps[(row << 8) + (colP ^ swz2)] = (_Float16)pa;
      Ps[((row + 32) << 8) + (colP ^ swz2)] = (_Float16)pb;
#pragma unroll
      for (int m = 1; m <= 16; m <<= 1) { pa += __shfl_xor(pa, m); pb += __shfl_xor(pb, m); }
      if (l31 == 0) {
        redsum[(wid << 6) + row] = pa;
        redsum[(wid << 6) + 32 + row] = pb;
      }
    }
    __syncthreads();
    if (tid < 64) {
      float s = 0.f;
#pragma unroll
      for (int w = 0; w < 8; ++w) s += redsum[(w << 6) + tid];
      lrow[tid] = lrow[tid] * rrow[tid] + s;
    }
    // ===================== PV (rescale + 32x32x16, depth-2 prefetch) =======
#pragma unroll
    for (int r = 0; r < 16; ++r) {
      int row = (r & 3) + ((r >> 2) << 3) + (lh << 2);
      float ra = rrow[row], rb = rrow[32 + row];
      acc00[r] *= ra; acc01[r] *= ra; acc02[r] *= ra;
      acc10[r] *= rb; acc11[r] *= rb; acc12[r] *= rb;
    }
    const _Float16* vb = vcol + s0;
    uint4 va0 = *reinterpret_cast<const uint4*>(vb);
    uint4 wa0 = *reinterpret_cast<const uint4*>(vb + 262144);
    uint4 xa0 = *reinterpret_cast<const uint4*>(vb + 524288);
    uint4 va1 = *reinterpret_cast<const uint4*>(vb + 16);
    uint4 wa1 = *reinterpret_cast<const uint4*>(vb + 262144 + 16);
    uint4 xa1 = *reinterpret_cast<const uint4*>(vb + 524288 + 16);
    const int pswz = (l31 & 7) << 3;
#pragma unroll
    for (int ks = 0; ks < 16; ++ks) {
      half8 b0 = __builtin_bit_cast(half8, va0);
      half8 b1 = __builtin_bit_cast(half8, wa0);
      half8 b2 = __builtin_bit_cast(half8, xa0);
      va0 = va1; wa0 = wa1; xa0 = xa1;
      if (ks < 14) {
        va1 = *reinterpret_cast<const uint4*>(vb + (ks + 2) * 16);
        wa1 = *reinterpret_cast<const uint4*>(vb + 262144 + (ks + 2) * 16);
        xa1 = *reinterpret_cast<const uint4*>(vb + 524288 + (ks + 2) * 16);
      }
      int pel = (ks << 4) + (lh << 3);
      half8 a0 = *reinterpret_cast<const half8*>(&Ps[(l31 << 8) + (pel ^ pswz)]);
      half8 a1 = *reinterpret_cast<const half8*>(&Ps[((32 + l31) << 8) + (pel ^ pswz)]);
      acc00 = __builtin_amdgcn_mfma_f32_32x32x16_f16(a0, b0, acc00, 0, 0, 0);
      acc01 = __builtin_amdgcn_mfma_f32_32x32x16_f16(a0, b1, acc01, 0, 0, 0);
      acc02 = __builtin_amdgcn_mfma_f32_32x32x16_f16(a0, b2, acc02, 0, 0, 0);
      acc10 = __builtin_amdgcn_mfma_f32_32x32x16_f16(a1, b0, acc10, 0, 0, 0);
      acc11 = __builtin_amdgcn_mfma_f32_32x32x16_f16(a1, b1, acc11, 0, 0, 0);
      acc12 = __builtin_amdgcn_mfma_f32_32x32x16_f16(a1, b2, acc12, 0, 0, 0);
    }
  }

  // ===================== fused LN + projection epilogue =====================
  float gw0 = gws[n0w + l31];
  float gw1 = gws[n0w + 32 + l31];
  float gw2 = gws[n0w + 64 + l31];
#pragma unroll
  for (int r = 0; r < 16; ++r) {
    int row = (r & 3) + ((r >> 2) << 3) + (lh << 2);
    {
      float y0 = acc00[r], y1 = acc01[r], y2 = acc02[r];
      float t1 = y0 + y1 + y2;
      float t2 = y0 * y0 + y1 * y1 + y2 * y2;
      float t3 = y0 * gw0 + y1 * gw1 + y2 * gw2;
#pragma unroll
      for (int m = 1; m <= 16; m <<= 1) {
        t1 += __shfl_xor(t1, m); t2 += __shfl_xor(t2, m); t3 += __shfl_xor(t3, m);
      }
      if (l31 == 0) { float* e = &epi[row * 24 + wid * 3]; e[0] = t1; e[1] = t2; e[2] = t3; }
    }
    {
      float y0 = acc10[r], y1 = acc11[r], y2 = acc12[r];
      float t1 = y0 + y1 + y2;
      float t2 = y0 * y0 + y1 * y1 + y2 * y2;
      float t3 = y0 * gw0 + y1 * gw1 + y2 * gw2;
#pragma unroll
      for (int m = 1; m <= 16; m <<= 1) {
        t1 += __shfl_xor(t1, m); t2 += __shfl_xor(t2, m); t3 += __shfl_xor(t3, m);
      }
      if (l31 == 0) { float* e = &epi[(row + 32) * 24 + wid * 3]; e[0] = t1; e[1] = t2; e[2] = t3; }
    }
  }
  __syncthreads();
  if (tid < 64) {
    float S1 = 0.f, S2 = 0.f, S3 = 0.f;
#pragma unroll
    for (int w = 0; w < 8; ++w) {
      const float* e = &epi[tid * 24 + w * 3];
      S1 += e[0]; S2 += e[1]; S3 += e[2];
    }
    float l = lrow[tid];
    float invl = 1.0f / l;
    float mu = S1 * invl * (1.0f / 768.0f);
    float ey2 = S2 * invl * invl * (1.0f / 768.0f);
    float var = ey2 - mu * mu;
    float rs = rsqrtf(var + 1e-5f);
    float res = rs * (S3 * invl - mu * scal[0]) + scal[1] + outb[0];
    out[bb * 8000 + c0 + tid] = res;
  }
}

// ---------------------------------------------------------------------------
extern "C" void kernel_launch(void* const* d_in, const int* in_sizes, int n_in,
                              void* d_out, int out_size, void* d_ws, size_t ws_size,
                              hipStream_t stream) {
  (void)in_sizes; (void)n_in; (void)out_size; (void)ws_size;
  const float* x     = (const float*)d_in[0];
  const float* qenc  = (const float*)d_in[1];
  const float* Wk    = (const float*)d_in[2];
  const float* Wv    = (const float*)d_in[3];
  const float* bv    = (const float*)d_in[4];
  const float* gam   = (const float*)d_in[5];
  const float* bet   = (const float*)d_in[6];
  const float* outw  = (const float*)d_in[7];
  const float* outb  = (const float*)d_in[8];
  float* out = (float*)d_out;

  char* ws = (char*)d_ws;
  _Float16* x_h  = (_Float16*)(ws);                  // 8192x768   = 12,582,912 B
  _Float16* wk_h = (_Float16*)(ws + 12582912);       // 768x768    =  1,179,648 B
  _Float16* wv_h = (_Float16*)(ws + 13762560);       // 768x768    =  1,179,648 B
  _Float16* K_h  = (_Float16*)(ws + 14942208);       // 8192x768   = 12,582,912 B
  _Float16* Vt_h = (_Float16*)(ws + 27525120);       // 768x8192   = 12,582,912 B
  // total 40,108,032 B

  cvt_kernel<<<6144, 256, 0, stream>>>(x, x_h, 1572864);
  cvt_kernel<<<576, 256, 0, stream>>>(Wk, wk_h, 147456);
  cvt_kernel<<<576, 256, 0, stream>>>(Wv, wv_h, 147456);
  // K[s,e] = x @ Wk^T   (row-major [8192 x 768])
  gemm_nt_f16<<<384, 256, 0, stream>>>(x_h, wk_h, K_h, nullptr, 8192, 768);
  // Vt[e,s] = Wv @ x^T + bv   ([768 x 8192], bias per row e)
  gemm_nt_f16<<<384, 256, 0, stream>>>(wv_h, x_h, Vt_h, bv, 768, 8192);
  attn_kernel<<<250, 512, 0, stream>>>(qenc, K_h, Vt_h, gam, bet, outw, outb, out);
}

// Round 2
// 756.606 us; speedup vs baseline: 1.2436x; 1.2436x over previous
//
#include <hip/hip_runtime.h>

// ---------------------------------------------------------------------------
// LabelCrossAttentionDE: out[b,c] = LN(softmax(Q K^T) V) . out_w + out_b
// B=2, S=4096, C=8000, D=768, SCALE=1 (fp16 MFMA path, fp32 accumulate)
// ---------------------------------------------------------------------------

typedef _Float16 half8  __attribute__((ext_vector_type(8)));
typedef _Float16 half4v __attribute__((ext_vector_type(4)));
typedef float    f32x4  __attribute__((ext_vector_type(4)));
typedef float    f32x16 __attribute__((ext_vector_type(16)));

#define L2E 1.44269504088896340736f

__device__ __forceinline__ void gld_lds16(_Float16* lds, const _Float16* g) {
  __builtin_amdgcn_global_load_lds(
      (const __attribute__((address_space(1))) unsigned int*)g,
      (__attribute__((address_space(3))) unsigned int*)lds, 16, 0, 0);
}

// ------------------------------ f32 -> f16 ---------------------------------
__global__ void cvt_kernel(const float* __restrict__ src, _Float16* __restrict__ dst, int n4) {
  int i = blockIdx.x * blockDim.x + threadIdx.x;
  if (i >= n4) return;
  float4 v = reinterpret_cast<const float4*>(src)[i];
  half4v h; h[0] = (_Float16)v.x; h[1] = (_Float16)v.y; h[2] = (_Float16)v.z; h[3] = (_Float16)v.w;
  reinterpret_cast<half4v*>(dst)[i] = h;
}

// ---------------- GEMM: C[M,N] f16 = A[M,768] @ Bt[N,768]^T (+bias[row]) ----
__global__ __launch_bounds__(256, 2) void gemm_nt_f16(
    const _Float16* __restrict__ A, const _Float16* __restrict__ Bt,
    _Float16* __restrict__ C, const float* __restrict__ bias, int M, int N)
{
  __shared__ __align__(16) _Float16 As[2][128 * 64];
  __shared__ __align__(16) _Float16 Bs[2][128 * 64];
  const int tid = threadIdx.x;
  const int lane = tid & 63, wid = tid >> 6;
  const int ntn = N >> 7;
  const int mtile = blockIdx.x / ntn, ntile = blockIdx.x - mtile * ntn;
  const int m0 = mtile << 7, n0 = ntile << 7;
  const int wm = wid >> 1, wn = wid & 1;

  f32x4 acc[4][4] = {};

  auto stage = [&](int buf, int kt) {
#pragma unroll
    for (int j = 0; j < 4; ++j) {
      int idx = (j << 8) + tid;
      int row = idx >> 3, slot = idx & 7;
      int gc = (kt << 6) + ((slot ^ (row & 7)) << 3);
      _Float16* ldsbase_a = &As[buf][(size_t)(((j << 8) + (wid << 6)) << 3)];
      _Float16* ldsbase_b = &Bs[buf][(size_t)(((j << 8) + (wid << 6)) << 3)];
      gld_lds16(ldsbase_a, &A[(size_t)(m0 + row) * 768 + gc]);
      gld_lds16(ldsbase_b, &Bt[(size_t)(n0 + row) * 768 + gc]);
    }
  };

  stage(0, 0);
  __syncthreads();

  for (int kt = 0; kt < 12; ++kt) {
    int cur = kt & 1;
    if (kt < 11) stage(cur ^ 1, kt + 1);
#pragma unroll
    for (int ks = 0; ks < 2; ++ks) {
      half8 a[4], b[4];
      int dloc = (ks << 5) + ((lane >> 4) << 3);
#pragma unroll
      for (int mi = 0; mi < 4; ++mi) {
        int row = (wm << 6) + (mi << 4) + (lane & 15);
        a[mi] = *reinterpret_cast<const half8*>(&As[cur][row * 64 + (dloc ^ ((row & 7) << 3))]);
      }
#pragma unroll
      for (int ni = 0; ni < 4; ++ni) {
        int row = (wn << 6) + (ni << 4) + (lane & 15);
        b[ni] = *reinterpret_cast<const half8*>(&Bs[cur][row * 64 + (dloc ^ ((row & 7) << 3))]);
      }
#pragma unroll
      for (int mi = 0; mi < 4; ++mi)
#pragma unroll
        for (int ni = 0; ni < 4; ++ni)
          acc[mi][ni] = __builtin_amdgcn_mfma_f32_16x16x32_f16(a[mi], b[ni], acc[mi][ni], 0, 0, 0);
    }
    __syncthreads();
  }

#pragma unroll
  for (int mi = 0; mi < 4; ++mi)
#pragma unroll
    for (int ni = 0; ni < 4; ++ni) {
      int col = n0 + (wn << 6) + (ni << 4) + (lane & 15);
#pragma unroll
      for (int r = 0; r < 4; ++r) {
        int row = m0 + (wm << 6) + (mi << 4) + ((lane >> 4) << 2) + r;
        float v = acc[mi][ni][r];
        if (bias) v += bias[row];
        C[(size_t)row * N + col] = (_Float16)v;
      }
    }
}

// --------------------------- fused attention -------------------------------
// Block: 8 waves, 32 c-rows, S in tiles of 256; 2 blocks/CU (16 waves).
// Swapped QK (A=K,B=Q) -> lane owns one c-column: in-lane softmax reductions,
// packed b64 P-writes. Conflict-free LDS strides (776 / 264 halfs).
#define QS_STRIDE 776
#define PS_STRIDE 264

__global__ __launch_bounds__(512, 4) void attn_kernel(
    const float* __restrict__ Qf, const _Float16* __restrict__ Kh,
    const _Float16* __restrict__ Vt,
    const float* __restrict__ gamma, const float* __restrict__ beta,
    const float* __restrict__ outw, const float* __restrict__ outb,
    float* __restrict__ out)
{
  __shared__ __align__(16) _Float16 Qs[32 * QS_STRIDE];  // 49,664 B
  __shared__ __align__(16) _Float16 Ps[32 * PS_STRIDE];  // 16,896 B
  __shared__ float redmax[8 * 32];
  __shared__ float redsum[8 * 32];
  __shared__ float mrow[32], lrow[32], rrow[32];
  __shared__ float gws[768];
  __shared__ float epi[32 * 25];
  __shared__ float scal[2];

  const int tid = threadIdx.x;
  const int lane = tid & 63;
  const int wid = tid >> 6;
  const int l31 = lane & 31;
  const int lh = lane >> 5;

  // bijective XCD swizzle for 500 blocks (q=62, r=4)
  int xcd = blockIdx.x & 7, i8 = blockIdx.x >> 3;
  int f = (xcd < 4) ? (xcd * 63 + i8) : (252 + (xcd - 4) * 62 + i8);
  const int bb = f / 250;
  const int ct = f - bb * 250;
  const int c0 = ct << 5;

  // ---- stage Q: fp32 -> fp16 into LDS (32 rows x 768) ----
#pragma unroll
  for (int i = 0; i < 12; ++i) {
    int idx = tid + (i << 9);
    int row = idx / 192, c4 = idx - row * 192;
    float4 v = reinterpret_cast<const float4*>(Qf)[(size_t)(c0 + row) * 192 + c4];
    half4v h; h[0] = (_Float16)v.x; h[1] = (_Float16)v.y; h[2] = (_Float16)v.z; h[3] = (_Float16)v.w;
    *reinterpret_cast<half4v*>(&Qs[row * QS_STRIDE + (c4 << 2)]) = h;
  }
  for (int i = tid; i < 768; i += 512) gws[i] = gamma[i] * outw[i];
  if (tid < 32) { mrow[tid] = -1e30f; lrow[tid] = 0.f; }
  __syncthreads();
  if (tid < 64) {  // scal[0]=sum(gamma*w), scal[1]=sum(beta*w)
    float g = 0.f, bw = 0.f;
#pragma unroll
    for (int j = 0; j < 12; ++j) { int d = tid + (j << 6); g += gws[d]; bw += beta[d] * outw[d]; }
#pragma unroll
    for (int m = 32; m; m >>= 1) { g += __shfl_xor(g, m); bw += __shfl_xor(bw, m); }
    if (tid == 0) { scal[0] = g; scal[1] = bw; }
  }

  f32x16 acc0 = {}, acc1 = {}, acc2 = {};  // O[c rows(16/lane) x v cols], 3 frags
  const int n0w = wid * 96;
  const _Float16* qrow = &Qs[l31 * QS_STRIDE + (lh << 3)];
  const _Float16* kcol = Kh + (size_t)((bb << 12) + (wid << 5) + l31) * 768 + (lh << 3);
  const _Float16* vcol = Vt + (size_t)(n0w + l31) * 8192 + (bb << 12) + (lh << 3);

  for (int st = 0; st < 16; ++st) {
    const int s0 = st << 8;
    // ===================== QK^T: A=K(s rows), B=Q(c cols), depth-4 ==========
    f32x16 qk = {};
    const _Float16* kb = kcol + (size_t)s0 * 768;
    uint4 kp[4];
#pragma unroll
    for (int j = 0; j < 4; ++j) kp[j] = *reinterpret_cast<const uint4*>(kb + (j << 4));
#pragma unroll
    for (int k = 0; k < 48; ++k) {
      half8 kf = __builtin_bit_cast(half8, kp[k & 3]);
      if (k < 44) kp[k & 3] = *reinterpret_cast<const uint4*>(kb + ((k + 4) << 4));
      half8 qf = *reinterpret_cast<const half8*>(qrow + (k << 4));
      qk = __builtin_amdgcn_mfma_f32_32x32x16_f16(kf, qf, qk, 0, 0, 0);
    }
    // early V prefetch (depth-1 set) — hides under softmax
    const _Float16* vb = vcol + s0;
    uint4 vp[2][3];
    vp[0][0] = *reinterpret_cast<const uint4*>(vb);
    vp[0][1] = *reinterpret_cast<const uint4*>(vb + 262144);
    vp[0][2] = *reinterpret_cast<const uint4*>(vb + 524288);

    // ===================== online softmax (lane owns col c=l31) ============
    float mx = fmaxf(fmaxf(fmaxf(qk[0], qk[1]), fmaxf(qk[2], qk[3])),
                     fmaxf(fmaxf(qk[4], qk[5]), fmaxf(qk[6], qk[7])));
    mx = fmaxf(mx, fmaxf(fmaxf(fmaxf(qk[8], qk[9]), fmaxf(qk[10], qk[11])),
                         fmaxf(fmaxf(qk[12], qk[13]), fmaxf(qk[14], qk[15]))));
    mx = fmaxf(mx, __shfl_xor(mx, 32));
    if (lane < 32) redmax[(wid << 5) + l31] = mx;
    __syncthreads();                                   // bar1
    if (tid < 32) {
      float pm = redmax[tid];
#pragma unroll
      for (int w = 1; w < 8; ++w) pm = fmaxf(pm, redmax[(w << 5) + tid]);
      float mo = mrow[tid];
      float mn = fmaxf(mo, pm);
      mrow[tid] = mn;
      rrow[tid] = exp2f((mo - mn) * L2E);
    }
    __syncthreads();                                   // bar2
    {
      float m = mrow[l31];
      float sum = 0.f;
      int sb = (wid << 5) + (lh << 2);
#pragma unroll
      for (int q2 = 0; q2 < 4; ++q2) {
        float p0 = exp2f((qk[4 * q2 + 0] - m) * L2E);
        float p1 = exp2f((qk[4 * q2 + 1] - m) * L2E);
        float p2 = exp2f((qk[4 * q2 + 2] - m) * L2E);
        float p3 = exp2f((qk[4 * q2 + 3] - m) * L2E);
        sum += (p0 + p1) + (p2 + p3);
        half4v h; h[0] = (_Float16)p0; h[1] = (_Float16)p1; h[2] = (_Float16)p2; h[3] = (_Float16)p3;
        *reinterpret_cast<half4v*>(&Ps[l31 * PS_STRIDE + sb + (q2 << 3)]) = h;
      }
      sum += __shfl_xor(sum, 32);
      if (lane < 32) redsum[(wid << 5) + l31] = sum;
    }
    __syncthreads();                                   // bar3
    if ((tid >> 5) == 2) {  // wave 1 lower half: lrow combine
      int c = tid & 31;
      float s = redsum[c];
#pragma unroll
      for (int w = 1; w < 8; ++w) s += redsum[(w << 5) + c];
      lrow[c] = lrow[c] * rrow[c] + s;
    }
    // ===================== rescale + PV (depth-2 per stream) ================
#pragma unroll
    for (int r = 0; r < 16; ++r) {
      float rs = rrow[(r & 3) + ((r >> 2) << 3) + (lh << 2)];
      acc0[r] *= rs; acc1[r] *= rs; acc2[r] *= rs;
    }
    vp[1][0] = *reinterpret_cast<const uint4*>(vb + 16);
    vp[1][1] = *reinterpret_cast<const uint4*>(vb + 262144 + 16);
    vp[1][2] = *reinterpret_cast<const uint4*>(vb + 524288 + 16);
#pragma unroll
    for (int ks = 0; ks < 16; ++ks) {
      half8 b0 = __builtin_bit_cast(half8, vp[ks & 1][0]);
      half8 b1 = __builtin_bit_cast(half8, vp[ks & 1][1]);
      half8 b2 = __builtin_bit_cast(half8, vp[ks & 1][2]);
      if (ks < 14) {
        vp[ks & 1][0] = *reinterpret_cast<const uint4*>(vb + ((ks + 2) << 4));
        vp[ks & 1][1] = *reinterpret_cast<const uint4*>(vb + 262144 + ((ks + 2) << 4));
        vp[ks & 1][2] = *reinterpret_cast<const uint4*>(vb + 524288 + ((ks + 2) << 4));
      }
      half8 pa = *reinterpret_cast<const half8*>(&Ps[l31 * PS_STRIDE + (ks << 4) + (lh << 3)]);
      acc0 = __builtin_amdgcn_mfma_f32_32x32x16_f16(pa, b0, acc0, 0, 0, 0);
      acc1 = __builtin_amdgcn_mfma_f32_32x32x16_f16(pa, b1, acc1, 0, 0, 0);
      acc2 = __builtin_amdgcn_mfma_f32_32x32x16_f16(pa, b2, acc2, 0, 0, 0);
    }
  }

  // ===================== fused LN + projection epilogue =====================
  float gw0 = gws[n0w + l31];
  float gw1 = gws[n0w + 32 + l31];
  float gw2 = gws[n0w + 64 + l31];
#pragma unroll
  for (int r = 0; r < 16; ++r) {
    float y0 = acc0[r], y1 = acc1[r], y2 = acc2[r];
    float t1 = y0 + y1 + y2;
    float t2 = y0 * y0 + y1 * y1 + y2 * y2;
    float t3 = y0 * gw0 + y1 * gw1 + y2 * gw2;
#pragma unroll
    for (int m = 1; m <= 16; m <<= 1) {
      t1 += __shfl_xor(t1, m); t2 += __shfl_xor(t2, m); t3 += __shfl_xor(t3, m);
    }
    if (l31 == 0) {
      int c = (r & 3) + ((r >> 2) << 3) + (lh << 2);
      float* e = &epi[c * 25 + wid * 3];
      e[0] = t1; e[1] = t2; e[2] = t3;
    }
  }
  __syncthreads();
  if (tid < 32) {
    float S1 = 0.f, S2 = 0.f, S3 = 0.f;
#pragma unroll
    for (int w = 0; w < 8; ++w) {
      const float* e = &epi[tid * 25 + w * 3];
      S1 += e[0]; S2 += e[1]; S3 += e[2];
    }
    float l = lrow[tid];
    float invl = 1.0f / l;
    float mu = S1 * invl * (1.0f / 768.0f);
    float ey2 = S2 * invl * invl * (1.0f / 768.0f);
    float var = ey2 - mu * mu;
    float rs = rsqrtf(var + 1e-5f);
    float res = rs * (S3 * invl - mu * scal[0]) + scal[1] + outb[0];
    out[bb * 8000 + c0 + tid] = res;
  }
}

// ---------------------------------------------------------------------------
extern "C" void kernel_launch(void* const* d_in, const int* in_sizes, int n_in,
                              void* d_out, int out_size, void* d_ws, size_t ws_size,
                              hipStream_t stream) {
  (void)in_sizes; (void)n_in; (void)out_size; (void)ws_size;
  const float* x     = (const float*)d_in[0];
  const float* qenc  = (const float*)d_in[1];
  const float* Wk    = (const float*)d_in[2];
  const float* Wv    = (const float*)d_in[3];
  const float* bv    = (const float*)d_in[4];
  const float* gam   = (const float*)d_in[5];
  const float* bet   = (const float*)d_in[6];
  const float* outw  = (const float*)d_in[7];
  const float* outb  = (const float*)d_in[8];
  float* out = (float*)d_out;

  char* ws = (char*)d_ws;
  _Float16* x_h  = (_Float16*)(ws);                  // 8192x768
  _Float16* wk_h = (_Float16*)(ws + 12582912);       // 768x768
  _Float16* wv_h = (_Float16*)(ws + 13762560);       // 768x768
  _Float16* K_h  = (_Float16*)(ws + 14942208);       // 8192x768
  _Float16* Vt_h = (_Float16*)(ws + 27525120);       // 768x8192

  cvt_kernel<<<6144, 256, 0, stream>>>(x, x_h, 1572864);
  cvt_kernel<<<576, 256, 0, stream>>>(Wk, wk_h, 147456);
  cvt_kernel<<<576, 256, 0, stream>>>(Wv, wv_h, 147456);
  gemm_nt_f16<<<384, 256, 0, stream>>>(x_h, wk_h, K_h, nullptr, 8192, 768);
  gemm_nt_f16<<<384, 256, 0, stream>>>(wv_h, x_h, Vt_h, bv, 768, 8192);
  attn_kernel<<<500, 512, 0, stream>>>(qenc, K_h, Vt_h, gam, bet, outw, outb, out);
}

// Round 3
// 347.394 us; speedup vs baseline: 2.7084x; 2.1780x over previous
//
#include <hip/hip_runtime.h>

// ---------------------------------------------------------------------------
// LabelCrossAttentionDE: out[b,c] = LN(softmax(Q K^T) V) . out_w + out_b
// B=2, S=4096, C=8000, D=768, SCALE=1 (fp16 MFMA path, fp32 accumulate)
// K and V are produced in MFMA *fragment order* so attention loads are
// fully-coalesced sequential 1KB wave-streams.
// ---------------------------------------------------------------------------

typedef _Float16 half8  __attribute__((ext_vector_type(8)));
typedef _Float16 half4v __attribute__((ext_vector_type(4)));
typedef float    f32x4  __attribute__((ext_vector_type(4)));
typedef float    f32x16 __attribute__((ext_vector_type(16)));

#define L2E 1.44269504088896340736f

__device__ __forceinline__ void gld_lds16(_Float16* lds, const _Float16* g) {
  __builtin_amdgcn_global_load_lds(
      (const __attribute__((address_space(1))) unsigned int*)g,
      (__attribute__((address_space(3))) unsigned int*)lds, 16, 0, 0);
}

// ------------------------------ f32 -> f16 ---------------------------------
__global__ void cvt_kernel(const float* __restrict__ src, _Float16* __restrict__ dst, int n4) {
  int i = blockIdx.x * blockDim.x + threadIdx.x;
  if (i >= n4) return;
  float4 v = reinterpret_cast<const float4*>(src)[i];
  half4v h; h[0] = (_Float16)v.x; h[1] = (_Float16)v.y; h[2] = (_Float16)v.z; h[3] = (_Float16)v.w;
  reinterpret_cast<half4v*>(dst)[i] = h;
}

// ---------------- GEMM: C = A[M,768] @ Bt[N,768]^T (+bias[row]) -------------
// MODE 1: K fragment layout.  element (row=s, col=d) ->
//         ((s>>5)*48 + (d>>4))*512 + (s&31)*16 + (d&15)
// MODE 2: V fragment layout.  element (row=e, col=s_global) ->
//         (((s>>12)*24 + (e>>5))*256 + ((s&4095)>>4))*512 + (e&31)*16 + (s&15)
template <int MODE>
__global__ __launch_bounds__(256, 2) void gemm_nt_f16(
    const _Float16* __restrict__ A, const _Float16* __restrict__ Bt,
    _Float16* __restrict__ C, const float* __restrict__ bias, int M, int N)
{
  __shared__ __align__(16) _Float16 As[2][128 * 64];
  __shared__ __align__(16) _Float16 Bs[2][128 * 64];
  const int tid = threadIdx.x;
  const int lane = tid & 63, wid = tid >> 6;
  const int ntn = N >> 7;
  const int mtile = blockIdx.x / ntn, ntile = blockIdx.x - mtile * ntn;
  const int m0 = mtile << 7, n0 = ntile << 7;
  const int wm = wid >> 1, wn = wid & 1;

  f32x4 acc[4][4] = {};

  auto stage = [&](int buf, int kt) {
#pragma unroll
    for (int j = 0; j < 4; ++j) {
      int idx = (j << 8) + tid;
      int row = idx >> 3, slot = idx & 7;
      int gc = (kt << 6) + ((slot ^ (row & 7)) << 3);
      _Float16* ldsbase_a = &As[buf][(size_t)(((j << 8) + (wid << 6)) << 3)];
      _Float16* ldsbase_b = &Bs[buf][(size_t)(((j << 8) + (wid << 6)) << 3)];
      gld_lds16(ldsbase_a, &A[(size_t)(m0 + row) * 768 + gc]);
      gld_lds16(ldsbase_b, &Bt[(size_t)(n0 + row) * 768 + gc]);
    }
  };

  stage(0, 0);
  __syncthreads();

  for (int kt = 0; kt < 12; ++kt) {
    int cur = kt & 1;
    if (kt < 11) stage(cur ^ 1, kt + 1);
#pragma unroll
    for (int ks = 0; ks < 2; ++ks) {
      half8 a[4], b[4];
      int dloc = (ks << 5) + ((lane >> 4) << 3);
#pragma unroll
      for (int mi = 0; mi < 4; ++mi) {
        int row = (wm << 6) + (mi << 4) + (lane & 15);
        a[mi] = *reinterpret_cast<const half8*>(&As[cur][row * 64 + (dloc ^ ((row & 7) << 3))]);
      }
#pragma unroll
      for (int ni = 0; ni < 4; ++ni) {
        int row = (wn << 6) + (ni << 4) + (lane & 15);
        b[ni] = *reinterpret_cast<const half8*>(&Bs[cur][row * 64 + (dloc ^ ((row & 7) << 3))]);
      }
#pragma unroll
      for (int mi = 0; mi < 4; ++mi)
#pragma unroll
        for (int ni = 0; ni < 4; ++ni)
          acc[mi][ni] = __builtin_amdgcn_mfma_f32_16x16x32_f16(a[mi], b[ni], acc[mi][ni], 0, 0, 0);
    }
    __syncthreads();
  }

#pragma unroll
  for (int mi = 0; mi < 4; ++mi)
#pragma unroll
    for (int ni = 0; ni < 4; ++ni) {
      int col = n0 + (wn << 6) + (ni << 4) + (lane & 15);
#pragma unroll
      for (int r = 0; r < 4; ++r) {
        int row = m0 + (wm << 6) + (mi << 4) + ((lane >> 4) << 2) + r;
        float v = acc[mi][ni][r];
        if (bias) v += bias[row];
        size_t a;
        if (MODE == 1) {
          a = ((size_t)(row >> 5) * 48 + (col >> 4)) * 512 + (row & 31) * 16 + (col & 15);
        } else {
          a = (((size_t)(col >> 12) * 24 + (row >> 5)) * 256 + ((col & 4095) >> 4)) * 512
              + (row & 31) * 16 + (col & 15);
        }
        C[a] = (_Float16)v;
      }
    }
}

// --------------------------- fused attention -------------------------------
// Block: 8 waves, 32 c-rows, S in tiles of 256; 2 blocks/CU (16 waves).
// Swapped QK (A=K,B=Q). K/V read from fragment-ordered buffers: every
// wave-load is contiguous 1KB. Conflict-free LDS strides (776 / 264 halfs).
#define QS_STRIDE 776
#define PS_STRIDE 264

__global__ __launch_bounds__(512, 4) void attn_kernel(
    const float* __restrict__ Qf, const _Float16* __restrict__ Kf,
    const _Float16* __restrict__ Vf,
    const float* __restrict__ gamma, const float* __restrict__ beta,
    const float* __restrict__ outw, const float* __restrict__ outb,
    float* __restrict__ out)
{
  __shared__ __align__(16) _Float16 Qs[32 * QS_STRIDE];  // 49,664 B
  __shared__ __align__(16) _Float16 Ps[32 * PS_STRIDE];  // 16,896 B
  __shared__ float redmax[8 * 32];
  __shared__ float redsum[8 * 32];
  __shared__ float mrow[32], lrow[32], rrow[32];
  __shared__ float gws[768];
  __shared__ float epi[32 * 25];
  __shared__ float scal[2];

  const int tid = threadIdx.x;
  const int lane = tid & 63;
  const int wid = tid >> 6;
  const int l31 = lane & 31;
  const int lh = lane >> 5;

  // bijective XCD swizzle for 500 blocks (q=62, r=4)
  int xcd = blockIdx.x & 7, i8 = blockIdx.x >> 3;
  int f = (xcd < 4) ? (xcd * 63 + i8) : (252 + (xcd - 4) * 62 + i8);
  const int bb = f / 250;
  const int ct = f - bb * 250;
  const int c0 = ct << 5;

  // ---- stage Q: fp32 -> fp16 into LDS (32 rows x 768) ----
#pragma unroll
  for (int i = 0; i < 12; ++i) {
    int idx = tid + (i << 9);
    int row = idx / 192, c4 = idx - row * 192;
    float4 v = reinterpret_cast<const float4*>(Qf)[(size_t)(c0 + row) * 192 + c4];
    half4v h; h[0] = (_Float16)v.x; h[1] = (_Float16)v.y; h[2] = (_Float16)v.z; h[3] = (_Float16)v.w;
    *reinterpret_cast<half4v*>(&Qs[row * QS_STRIDE + (c4 << 2)]) = h;
  }
  for (int i = tid; i < 768; i += 512) gws[i] = gamma[i] * outw[i];
  if (tid < 32) { mrow[tid] = -1e30f; lrow[tid] = 0.f; }
  __syncthreads();
  if (tid < 64) {  // scal[0]=sum(gamma*w), scal[1]=sum(beta*w)
    float g = 0.f, bw = 0.f;
#pragma unroll
    for (int j = 0; j < 12; ++j) { int d = tid + (j << 6); g += gws[d]; bw += beta[d] * outw[d]; }
#pragma unroll
    for (int m = 32; m; m >>= 1) { g += __shfl_xor(g, m); bw += __shfl_xor(bw, m); }
    if (tid == 0) { scal[0] = g; scal[1] = bw; }
  }

  f32x16 acc0 = {}, acc1 = {}, acc2 = {};  // O[c rows(16/lane) x v cols], 3 frags
  const int n0w = wid * 96;
  const _Float16* qrow = &Qs[l31 * QS_STRIDE + (lh << 3)];
  const int laneoff = l31 * 16 + lh * 8;
  // K fragment stream base: s5 = bb*128 + st*8 + wid, step k = +512 halfs
  const _Float16* kfb = Kf + ((size_t)(bb * 128 + wid) * 48) * 512 + laneoff;
  // V fragment stream base: e5 = bb*24 + wid*3 + {0,1,2}, step ks = +512 halfs
  const _Float16* vfb = Vf + ((size_t)(bb * 24 + wid * 3) * 256) * 512 + laneoff;

  for (int st = 0; st < 16; ++st) {
    // ===================== QK^T: A=K(s rows), B=Q(c cols), depth-4 ==========
    f32x16 qk = {};
    const _Float16* kb = kfb + (size_t)st * (8 * 48 * 512);
    uint4 kp[4];
#pragma unroll
    for (int j = 0; j < 4; ++j) kp[j] = *reinterpret_cast<const uint4*>(kb + j * 512);
#pragma unroll
    for (int k = 0; k < 48; ++k) {
      half8 kf = __builtin_bit_cast(half8, kp[k & 3]);
      if (k < 44) kp[k & 3] = *reinterpret_cast<const uint4*>(kb + (k + 4) * 512);
      half8 qf = *reinterpret_cast<const half8*>(qrow + (k << 4));
      qk = __builtin_amdgcn_mfma_f32_32x32x16_f16(kf, qf, qk, 0, 0, 0);
    }
    // early V prefetch (depth-1 set) — hides under softmax
    const _Float16* vb = vfb + (size_t)st * (16 * 512);
    uint4 vp[2][3];
    vp[0][0] = *reinterpret_cast<const uint4*>(vb);
    vp[0][1] = *reinterpret_cast<const uint4*>(vb + 131072);
    vp[0][2] = *reinterpret_cast<const uint4*>(vb + 262144);

    // ===================== online softmax (lane owns col c=l31) ============
    float mx = fmaxf(fmaxf(fmaxf(qk[0], qk[1]), fmaxf(qk[2], qk[3])),
                     fmaxf(fmaxf(qk[4], qk[5]), fmaxf(qk[6], qk[7])));
    mx = fmaxf(mx, fmaxf(fmaxf(fmaxf(qk[8], qk[9]), fmaxf(qk[10], qk[11])),
                         fmaxf(fmaxf(qk[12], qk[13]), fmaxf(qk[14], qk[15]))));
    mx = fmaxf(mx, __shfl_xor(mx, 32));
    if (lane < 32) redmax[(wid << 5) + l31] = mx;
    __syncthreads();                                   // bar1
    if (tid < 32) {
      float pm = redmax[tid];
#pragma unroll
      for (int w = 1; w < 8; ++w) pm = fmaxf(pm, redmax[(w << 5) + tid]);
      float mo = mrow[tid];
      float mn = fmaxf(mo, pm);
      mrow[tid] = mn;
      rrow[tid] = exp2f((mo - mn) * L2E);
    }
    __syncthreads();                                   // bar2
    {
      float m = mrow[l31];
      float sum = 0.f;
      int sb = (wid << 5) + (lh << 2);
#pragma unroll
      for (int q2 = 0; q2 < 4; ++q2) {
        float p0 = exp2f((qk[4 * q2 + 0] - m) * L2E);
        float p1 = exp2f((qk[4 * q2 + 1] - m) * L2E);
        float p2 = exp2f((qk[4 * q2 + 2] - m) * L2E);
        float p3 = exp2f((qk[4 * q2 + 3] - m) * L2E);
        sum += (p0 + p1) + (p2 + p3);
        half4v h; h[0] = (_Float16)p0; h[1] = (_Float16)p1; h[2] = (_Float16)p2; h[3] = (_Float16)p3;
        *reinterpret_cast<half4v*>(&Ps[l31 * PS_STRIDE + sb + (q2 << 3)]) = h;
      }
      sum += __shfl_xor(sum, 32);
      if (lane < 32) redsum[(wid << 5) + l31] = sum;
    }
    __syncthreads();                                   // bar3
    if ((tid >> 5) == 2) {  // wave 1 lower half: lrow combine
      int c = tid & 31;
      float s = redsum[c];
#pragma unroll
      for (int w = 1; w < 8; ++w) s += redsum[(w << 5) + c];
      lrow[c] = lrow[c] * rrow[c] + s;
    }
    // ===================== rescale + PV (depth-2 per stream) ================
#pragma unroll
    for (int r = 0; r < 16; ++r) {
      float rs = rrow[(r & 3) + ((r >> 2) << 3) + (lh << 2)];
      acc0[r] *= rs; acc1[r] *= rs; acc2[r] *= rs;
    }
    vp[1][0] = *reinterpret_cast<const uint4*>(vb + 512);
    vp[1][1] = *reinterpret_cast<const uint4*>(vb + 131072 + 512);
    vp[1][2] = *reinterpret_cast<const uint4*>(vb + 262144 + 512);
#pragma unroll
    for (int ks = 0; ks < 16; ++ks) {
      half8 b0 = __builtin_bit_cast(half8, vp[ks & 1][0]);
      half8 b1 = __builtin_bit_cast(half8, vp[ks & 1][1]);
      half8 b2 = __builtin_bit_cast(half8, vp[ks & 1][2]);
      if (ks < 14) {
        vp[ks & 1][0] = *reinterpret_cast<const uint4*>(vb + (ks + 2) * 512);
        vp[ks & 1][1] = *reinterpret_cast<const uint4*>(vb + 131072 + (ks + 2) * 512);
        vp[ks & 1][2] = *reinterpret_cast<const uint4*>(vb + 262144 + (ks + 2) * 512);
      }
      half8 pa = *reinterpret_cast<const half8*>(&Ps[l31 * PS_STRIDE + (ks << 4) + (lh << 3)]);
      acc0 = __builtin_amdgcn_mfma_f32_32x32x16_f16(pa, b0, acc0, 0, 0, 0);
      acc1 = __builtin_amdgcn_mfma_f32_32x32x16_f16(pa, b1, acc1, 0, 0, 0);
      acc2 = __builtin_amdgcn_mfma_f32_32x32x16_f16(pa, b2, acc2, 0, 0, 0);
    }
  }

  // ===================== fused LN + projection epilogue =====================
  float gw0 = gws[n0w + l31];
  float gw1 = gws[n0w + 32 + l31];
  float gw2 = gws[n0w + 64 + l31];
#pragma unroll
  for (int r = 0; r < 16; ++r) {
    float y0 = acc0[r], y1 = acc1[r], y2 = acc2[r];
    float t1 = y0 + y1 + y2;
    float t2 = y0 * y0 + y1 * y1 + y2 * y2;
    float t3 = y0 * gw0 + y1 * gw1 + y2 * gw2;
#pragma unroll
    for (int m = 1; m <= 16; m <<= 1) {
      t1 += __shfl_xor(t1, m); t2 += __shfl_xor(t2, m); t3 += __shfl_xor(t3, m);
    }
    if (l31 == 0) {
      int c = (r & 3) + ((r >> 2) << 3) + (lh << 2);
      float* e = &epi[c * 25 + wid * 3];
      e[0] = t1; e[1] = t2; e[2] = t3;
    }
  }
  __syncthreads();
  if (tid < 32) {
    float S1 = 0.f, S2 = 0.f, S3 = 0.f;
#pragma unroll
    for (int w = 0; w < 8; ++w) {
      const float* e = &epi[tid * 25 + w * 3];
      S1 += e[0]; S2 += e[1]; S3 += e[2];
    }
    float l = lrow[tid];
    float invl = 1.0f / l;
    float mu = S1 * invl * (1.0f / 768.0f);
    float ey2 = S2 * invl * invl * (1.0f / 768.0f);
    float var = ey2 - mu * mu;
    float rs = rsqrtf(var + 1e-5f);
    float res = rs * (S3 * invl - mu * scal[0]) + scal[1] + outb[0];
    out[bb * 8000 + c0 + tid] = res;
  }
}

// ---------------------------------------------------------------------------
extern "C" void kernel_launch(void* const* d_in, const int* in_sizes, int n_in,
                              void* d_out, int out_size, void* d_ws, size_t ws_size,
                              hipStream_t stream) {
  (void)in_sizes; (void)n_in; (void)out_size; (void)ws_size;
  const float* x     = (const float*)d_in[0];
  const float* qenc  = (const float*)d_in[1];
  const float* Wk    = (const float*)d_in[2];
  const float* Wv    = (const float*)d_in[3];
  const float* bv    = (const float*)d_in[4];
  const float* gam   = (const float*)d_in[5];
  const float* bet   = (const float*)d_in[6];
  const float* outw  = (const float*)d_in[7];
  const float* outb  = (const float*)d_in[8];
  float* out = (float*)d_out;

  char* ws = (char*)d_ws;
  _Float16* x_h  = (_Float16*)(ws);                  // 8192x768
  _Float16* wk_h = (_Float16*)(ws + 12582912);       // 768x768
  _Float16* wv_h = (_Float16*)(ws + 13762560);       // 768x768
  _Float16* K_f  = (_Float16*)(ws + 14942208);       // frag layout, 12.6 MB
  _Float16* V_f  = (_Float16*)(ws + 27525120);       // frag layout, 12.6 MB

  cvt_kernel<<<6144, 256, 0, stream>>>(x, x_h, 1572864);
  cvt_kernel<<<576, 256, 0, stream>>>(Wk, wk_h, 147456);
  cvt_kernel<<<576, 256, 0, stream>>>(Wv, wv_h, 147456);
  // K[s,e] = x @ Wk^T  -> fragment layout
  gemm_nt_f16<1><<<384, 256, 0, stream>>>(x_h, wk_h, K_f, nullptr, 8192, 768);
  // V^T[e,s] = Wv @ x^T + bv -> fragment layout
  gemm_nt_f16<2><<<384, 256, 0, stream>>>(wv_h, x_h, V_f, bv, 768, 8192);
  attn_kernel<<<500, 512, 0, stream>>>(qenc, K_f, V_f, gam, bet, outw, outb, out);
}

// Round 4
// 318.098 us; speedup vs baseline: 2.9579x; 1.0921x over previous
//
#include <hip/hip_runtime.h>

// ---------------------------------------------------------------------------
// LabelCrossAttentionDE: out[b,c] = LN(softmax(Q K^T) V) . out_w + out_b
// B=2, S=4096, C=8000, D=768, SCALE=1 (fp16 MFMA path, fp32 accumulate)
// K/V in MFMA fragment order (coalesced 1KB wave-streams).
// Attention: CT=64 c-rows/block, 1 block/CU -> K/V bytes amortized over
// 2 MFMAs each; softmax state replicated in registers (2 barriers/tile).
// ---------------------------------------------------------------------------

typedef _Float16 half8  __attribute__((ext_vector_type(8)));
typedef _Float16 half4v __attribute__((ext_vector_type(4)));
typedef float    f32x4  __attribute__((ext_vector_type(4)));
typedef float    f32x16 __attribute__((ext_vector_type(16)));

#define L2E 1.44269504088896340736f

__device__ __forceinline__ void gld_lds16(_Float16* lds, const _Float16* g) {
  __builtin_amdgcn_global_load_lds(
      (const __attribute__((address_space(1))) unsigned int*)g,
      (__attribute__((address_space(3))) unsigned int*)lds, 16, 0, 0);
}

// ------------------------------ f32 -> f16 ---------------------------------
__global__ void cvt_kernel(const float* __restrict__ src, _Float16* __restrict__ dst, int n4) {
  int i = blockIdx.x * blockDim.x + threadIdx.x;
  if (i >= n4) return;
  float4 v = reinterpret_cast<const float4*>(src)[i];
  half4v h; h[0] = (_Float16)v.x; h[1] = (_Float16)v.y; h[2] = (_Float16)v.z; h[3] = (_Float16)v.w;
  reinterpret_cast<half4v*>(dst)[i] = h;
}

// ---------------- GEMM: C = A[M,768] @ Bt[N,768]^T (+bias[row]) -------------
// MODE 1: K fragment layout.  (row=s, col=d) ->
//         ((s>>5)*48 + (d>>4))*512 + (s&31)*16 + (d&15)
// MODE 2: V fragment layout.  (row=e, col=s_global) ->
//         (((s>>12)*24 + (e>>5))*256 + ((s&4095)>>4))*512 + (e&31)*16 + (s&15)
template <int MODE>
__global__ __launch_bounds__(256, 2) void gemm_nt_f16(
    const _Float16* __restrict__ A, const _Float16* __restrict__ Bt,
    _Float16* __restrict__ C, const float* __restrict__ bias, int M, int N)
{
  __shared__ __align__(16) _Float16 As[2][128 * 64];
  __shared__ __align__(16) _Float16 Bs[2][128 * 64];
  const int tid = threadIdx.x;
  const int lane = tid & 63, wid = tid >> 6;
  const int ntn = N >> 7;
  const int mtile = blockIdx.x / ntn, ntile = blockIdx.x - mtile * ntn;
  const int m0 = mtile << 7, n0 = ntile << 7;
  const int wm = wid >> 1, wn = wid & 1;

  f32x4 acc[4][4] = {};

  auto stage = [&](int buf, int kt) {
#pragma unroll
    for (int j = 0; j < 4; ++j) {
      int idx = (j << 8) + tid;
      int row = idx >> 3, slot = idx & 7;
      int gc = (kt << 6) + ((slot ^ (row & 7)) << 3);
      _Float16* ldsbase_a = &As[buf][(size_t)(((j << 8) + (wid << 6)) << 3)];
      _Float16* ldsbase_b = &Bs[buf][(size_t)(((j << 8) + (wid << 6)) << 3)];
      gld_lds16(ldsbase_a, &A[(size_t)(m0 + row) * 768 + gc]);
      gld_lds16(ldsbase_b, &Bt[(size_t)(n0 + row) * 768 + gc]);
    }
  };

  stage(0, 0);
  __syncthreads();

  for (int kt = 0; kt < 12; ++kt) {
    int cur = kt & 1;
    if (kt < 11) stage(cur ^ 1, kt + 1);
#pragma unroll
    for (int ks = 0; ks < 2; ++ks) {
      half8 a[4], b[4];
      int dloc = (ks << 5) + ((lane >> 4) << 3);
#pragma unroll
      for (int mi = 0; mi < 4; ++mi) {
        int row = (wm << 6) + (mi << 4) + (lane & 15);
        a[mi] = *reinterpret_cast<const half8*>(&As[cur][row * 64 + (dloc ^ ((row & 7) << 3))]);
      }
#pragma unroll
      for (int ni = 0; ni < 4; ++ni) {
        int row = (wn << 6) + (ni << 4) + (lane & 15);
        b[ni] = *reinterpret_cast<const half8*>(&Bs[cur][row * 64 + (dloc ^ ((row & 7) << 3))]);
      }
#pragma unroll
      for (int mi = 0; mi < 4; ++mi)
#pragma unroll
        for (int ni = 0; ni < 4; ++ni)
          acc[mi][ni] = __builtin_amdgcn_mfma_f32_16x16x32_f16(a[mi], b[ni], acc[mi][ni], 0, 0, 0);
    }
    __syncthreads();
  }

#pragma unroll
  for (int mi = 0; mi < 4; ++mi)
#pragma unroll
    for (int ni = 0; ni < 4; ++ni) {
      int col = n0 + (wn << 6) + (ni << 4) + (lane & 15);
#pragma unroll
      for (int r = 0; r < 4; ++r) {
        int row = m0 + (wm << 6) + (mi << 4) + ((lane >> 4) << 2) + r;
        float v = acc[mi][ni][r];
        if (bias) v += bias[row];
        size_t a;
        if (MODE == 1) {
          a = ((size_t)(row >> 5) * 48 + (col >> 4)) * 512 + (row & 31) * 16 + (col & 15);
        } else {
          a = (((size_t)(col >> 12) * 24 + (row >> 5)) * 256 + ((col & 4095) >> 4)) * 512
              + (row & 31) * 16 + (col & 15);
        }
        C[a] = (_Float16)v;
      }
    }
}

// --------------------------- fused attention -------------------------------
// 8 waves, 64 c-rows/block, S tiles of 256; 1 block/CU (250 blocks).
// Swapped QK (A=K,B=Q): lane owns cols c=l31 and c=l31+32. Softmax running
// state (m, r, l) replicated in registers across waves; 2 barriers per tile.
#define QS_STRIDE 776
#define PS_STRIDE 264

__global__ __launch_bounds__(512, 2) void attn_kernel(
    const float* __restrict__ Qf, const _Float16* __restrict__ Kf,
    const _Float16* __restrict__ Vf,
    const float* __restrict__ gamma, const float* __restrict__ beta,
    const float* __restrict__ outw, const float* __restrict__ outb,
    float* __restrict__ out)
{
  __shared__ __align__(16) _Float16 Qs[64 * QS_STRIDE];  // 99,328 B
  __shared__ __align__(16) _Float16 Ps[64 * PS_STRIDE];  // 33,792 B
  __shared__ float redmax[8 * 64];
  __shared__ float redsum[8 * 64];
  __shared__ float gws[768];
  __shared__ float epi[64 * 25];
  __shared__ float lrowS[64];
  __shared__ float scal[2];

  const int tid = threadIdx.x;
  const int lane = tid & 63;
  const int wid = tid >> 6;
  const int l31 = lane & 31;
  const int lh = lane >> 5;

  // bijective XCD swizzle for 250 blocks (q=31, r=2)
  int xcd = blockIdx.x & 7, i8 = blockIdx.x >> 3;
  int f = (xcd < 2) ? (xcd * 32 + i8) : (64 + (xcd - 2) * 31 + i8);
  const int bb = f / 125;
  const int ct = f - bb * 125;
  const int c0 = ct << 6;

  // ---- stage Q: fp32 -> fp16 into LDS (64 rows x 768) ----
#pragma unroll
  for (int i = 0; i < 24; ++i) {
    int idx = tid + (i << 9);
    int row = idx / 192, c4 = idx - row * 192;
    float4 v = reinterpret_cast<const float4*>(Qf)[(size_t)(c0 + row) * 192 + c4];
    half4v h; h[0] = (_Float16)v.x; h[1] = (_Float16)v.y; h[2] = (_Float16)v.z; h[3] = (_Float16)v.w;
    *reinterpret_cast<half4v*>(&Qs[row * QS_STRIDE + (c4 << 2)]) = h;
  }
  for (int i = tid; i < 768; i += 512) gws[i] = gamma[i] * outw[i];
  __syncthreads();
  if (tid < 64) {  // scal[0]=sum(gamma*w), scal[1]=sum(beta*w)
    float g = 0.f, bw = 0.f;
#pragma unroll
    for (int j = 0; j < 12; ++j) { int d = tid + (j << 6); g += gws[d]; bw += beta[d] * outw[d]; }
#pragma unroll
    for (int m = 32; m; m >>= 1) { g += __shfl_xor(g, m); bw += __shfl_xor(bw, m); }
    if (tid == 0) { scal[0] = g; scal[1] = bw; }
  }

  // per-lane replicated softmax state for columns c=l31 (0) and c=l31+32 (1)
  float mrow0 = -1e30f, mrow1 = -1e30f, lrow0 = 0.f, lrow1 = 0.f;

  f32x16 acc00 = {}, acc01 = {}, acc02 = {};  // rows c 0-31  x 96 e-cols
  f32x16 acc10 = {}, acc11 = {}, acc12 = {};  // rows c 32-63 x 96 e-cols
  const int n0w = wid * 96;
  const _Float16* qrow0 = &Qs[l31 * QS_STRIDE + (lh << 3)];
  const _Float16* qrow1 = qrow0 + 32 * QS_STRIDE;
  const int laneoff = l31 * 16 + lh * 8;
  const _Float16* kfb = Kf + ((size_t)(bb * 128 + wid) * 48) * 512 + laneoff;
  const _Float16* vfb = Vf + ((size_t)(bb * 24 + wid * 3) * 256) * 512 + laneoff;

  for (int st = 0; st < 16; ++st) {
    // ===================== QK^T: A=K(32 s-rows), B=Q(2 c-frags), depth-4 ====
    f32x16 qk0 = {}, qk1 = {};
    const _Float16* kb = kfb + (size_t)st * (8 * 48 * 512);
    uint4 kp[4];
#pragma unroll
    for (int j = 0; j < 4; ++j) kp[j] = *reinterpret_cast<const uint4*>(kb + j * 512);
#pragma unroll
    for (int k = 0; k < 48; ++k) {
      half8 kf = __builtin_bit_cast(half8, kp[k & 3]);
      if (k < 44) kp[k & 3] = *reinterpret_cast<const uint4*>(kb + (k + 4) * 512);
      half8 qf0 = *reinterpret_cast<const half8*>(qrow0 + (k << 4));
      half8 qf1 = *reinterpret_cast<const half8*>(qrow1 + (k << 4));
      qk0 = __builtin_amdgcn_mfma_f32_32x32x16_f16(kf, qf0, qk0, 0, 0, 0);
      qk1 = __builtin_amdgcn_mfma_f32_32x32x16_f16(kf, qf1, qk1, 0, 0, 0);
    }
    // early V prefetch — hides under softmax
    const _Float16* vb = vfb + (size_t)st * (16 * 512);
    uint4 vp[2][3];
    vp[0][0] = *reinterpret_cast<const uint4*>(vb);
    vp[0][1] = *reinterpret_cast<const uint4*>(vb + 131072);
    vp[0][2] = *reinterpret_cast<const uint4*>(vb + 262144);

    // ===================== softmax (state in registers, 2 barriers) =========
    float mx0 = qk0[0], mx1 = qk1[0];
#pragma unroll
    for (int r = 1; r < 16; ++r) { mx0 = fmaxf(mx0, qk0[r]); mx1 = fmaxf(mx1, qk1[r]); }
    mx0 = fmaxf(mx0, __shfl_xor(mx0, 32));
    mx1 = fmaxf(mx1, __shfl_xor(mx1, 32));
    if (lh == 0) {
      redmax[(wid << 6) + l31] = mx0;
      redmax[(wid << 6) + 32 + l31] = mx1;
    }
    __syncthreads();                                   // bar A
    float pm0 = redmax[l31], pm1 = redmax[32 + l31];
#pragma unroll
    for (int w = 1; w < 8; ++w) {
      pm0 = fmaxf(pm0, redmax[(w << 6) + l31]);
      pm1 = fmaxf(pm1, redmax[(w << 6) + 32 + l31]);
    }
    float mn0 = fmaxf(mrow0, pm0), mn1 = fmaxf(mrow1, pm1);
    float rr0 = exp2f((mrow0 - mn0) * L2E), rr1 = exp2f((mrow1 - mn1) * L2E);
    mrow0 = mn0; mrow1 = mn1;

    float sum0 = 0.f, sum1 = 0.f;
    const int sb = (wid << 5) + (lh << 2);
#pragma unroll
    for (int q2 = 0; q2 < 4; ++q2) {
      float p0 = exp2f((qk0[4 * q2 + 0] - mn0) * L2E);
      float p1 = exp2f((qk0[4 * q2 + 1] - mn0) * L2E);
      float p2 = exp2f((qk0[4 * q2 + 2] - mn0) * L2E);
      float p3 = exp2f((qk0[4 * q2 + 3] - mn0) * L2E);
      sum0 += (p0 + p1) + (p2 + p3);
      half4v h; h[0] = (_Float16)p0; h[1] = (_Float16)p1; h[2] = (_Float16)p2; h[3] = (_Float16)p3;
      *reinterpret_cast<half4v*>(&Ps[l31 * PS_STRIDE + sb + (q2 << 3)]) = h;
      float u0 = exp2f((qk1[4 * q2 + 0] - mn1) * L2E);
      float u1 = exp2f((qk1[4 * q2 + 1] - mn1) * L2E);
      float u2 = exp2f((qk1[4 * q2 + 2] - mn1) * L2E);
      float u3 = exp2f((qk1[4 * q2 + 3] - mn1) * L2E);
      sum1 += (u0 + u1) + (u2 + u3);
      half4v h2; h2[0] = (_Float16)u0; h2[1] = (_Float16)u1; h2[2] = (_Float16)u2; h2[3] = (_Float16)u3;
      *reinterpret_cast<half4v*>(&Ps[(32 + l31) * PS_STRIDE + sb + (q2 << 3)]) = h2;
    }
    sum0 += __shfl_xor(sum0, 32);
    sum1 += __shfl_xor(sum1, 32);
    if (lh == 0) {
      redsum[(wid << 6) + l31] = sum0;
      redsum[(wid << 6) + 32 + l31] = sum1;
    }
    // rescale accumulators while redsum settles (register-only)
#pragma unroll
    for (int r = 0; r < 16; ++r) {
      int crow = (r & 3) + ((r >> 2) << 3) + (lh << 2);
      float rs0 = __shfl(rr0, crow);
      float rs1 = __shfl(rr1, crow);
      acc00[r] *= rs0; acc01[r] *= rs0; acc02[r] *= rs0;
      acc10[r] *= rs1; acc11[r] *= rs1; acc12[r] *= rs1;
    }
    vp[1][0] = *reinterpret_cast<const uint4*>(vb + 512);
    vp[1][1] = *reinterpret_cast<const uint4*>(vb + 131072 + 512);
    vp[1][2] = *reinterpret_cast<const uint4*>(vb + 262144 + 512);
    __syncthreads();                                   // bar B
    {
      float s0 = redsum[l31], s1 = redsum[32 + l31];
#pragma unroll
      for (int w = 1; w < 8; ++w) {
        s0 += redsum[(w << 6) + l31];
        s1 += redsum[(w << 6) + 32 + l31];
      }
      lrow0 = lrow0 * rr0 + s0;
      lrow1 = lrow1 * rr1 + s1;
    }
    // ===================== PV: 2 P-frags x 3 V-frags ========================
#pragma unroll
    for (int ks = 0; ks < 16; ++ks) {
      half8 b0 = __builtin_bit_cast(half8, vp[ks & 1][0]);
      half8 b1 = __builtin_bit_cast(half8, vp[ks & 1][1]);
      half8 b2 = __builtin_bit_cast(half8, vp[ks & 1][2]);
      if (ks < 14) {
        vp[ks & 1][0] = *reinterpret_cast<const uint4*>(vb + (ks + 2) * 512);
        vp[ks & 1][1] = *reinterpret_cast<const uint4*>(vb + 131072 + (ks + 2) * 512);
        vp[ks & 1][2] = *reinterpret_cast<const uint4*>(vb + 262144 + (ks + 2) * 512);
      }
      half8 pa0 = *reinterpret_cast<const half8*>(&Ps[l31 * PS_STRIDE + (ks << 4) + (lh << 3)]);
      half8 pa1 = *reinterpret_cast<const half8*>(&Ps[(32 + l31) * PS_STRIDE + (ks << 4) + (lh << 3)]);
      acc00 = __builtin_amdgcn_mfma_f32_32x32x16_f16(pa0, b0, acc00, 0, 0, 0);
      acc01 = __builtin_amdgcn_mfma_f32_32x32x16_f16(pa0, b1, acc01, 0, 0, 0);
      acc02 = __builtin_amdgcn_mfma_f32_32x32x16_f16(pa0, b2, acc02, 0, 0, 0);
      acc10 = __builtin_amdgcn_mfma_f32_32x32x16_f16(pa1, b0, acc10, 0, 0, 0);
      acc11 = __builtin_amdgcn_mfma_f32_32x32x16_f16(pa1, b1, acc11, 0, 0, 0);
      acc12 = __builtin_amdgcn_mfma_f32_32x32x16_f16(pa1, b2, acc12, 0, 0, 0);
    }
  }

  // ===================== fused LN + projection epilogue =====================
  if (wid == 0 && lh == 0) { lrowS[l31] = lrow0; lrowS[32 + l31] = lrow1; }
  float gw0 = gws[n0w + l31];
  float gw1 = gws[n0w + 32 + l31];
  float gw2 = gws[n0w + 64 + l31];
#pragma unroll
  for (int r = 0; r < 16; ++r) {
    int c = (r & 3) + ((r >> 2) << 3) + (lh << 2);
    {
      float y0 = acc00[r], y1 = acc01[r], y2 = acc02[r];
      float t1 = y0 + y1 + y2;
      float t2 = y0 * y0 + y1 * y1 + y2 * y2;
      float t3 = y0 * gw0 + y1 * gw1 + y2 * gw2;
#pragma unroll
      for (int m = 1; m <= 16; m <<= 1) {
        t1 += __shfl_xor(t1, m); t2 += __shfl_xor(t2, m); t3 += __shfl_xor(t3, m);
      }
      if (l31 == 0) { float* e = &epi[c * 25 + wid * 3]; e[0] = t1; e[1] = t2; e[2] = t3; }
    }
    {
      float y0 = acc10[r], y1 = acc11[r], y2 = acc12[r];
      float t1 = y0 + y1 + y2;
      float t2 = y0 * y0 + y1 * y1 + y2 * y2;
      float t3 = y0 * gw0 + y1 * gw1 + y2 * gw2;
#pragma unroll
      for (int m = 1; m <= 16; m <<= 1) {
        t1 += __shfl_xor(t1, m); t2 += __shfl_xor(t2, m); t3 += __shfl_xor(t3, m);
      }
      if (l31 == 0) { float* e = &epi[(32 + c) * 25 + wid * 3]; e[0] = t1; e[1] = t2; e[2] = t3; }
    }
  }
  __syncthreads();
  if (tid < 64) {
    float S1 = 0.f, S2 = 0.f, S3 = 0.f;
#pragma unroll
    for (int w = 0; w < 8; ++w) {
      const float* e = &epi[tid * 25 + w * 3];
      S1 += e[0]; S2 += e[1]; S3 += e[2];
    }
    float l = lrowS[tid];
    float invl = 1.0f / l;
    float mu = S1 * invl * (1.0f / 768.0f);
    float ey2 = S2 * invl * invl * (1.0f / 768.0f);
    float var = ey2 - mu * mu;
    float rs = rsqrtf(var + 1e-5f);
    float res = rs * (S3 * invl - mu * scal[0]) + scal[1] + outb[0];
    out[bb * 8000 + c0 + tid] = res;
  }
}

// ---------------------------------------------------------------------------
extern "C" void kernel_launch(void* const* d_in, const int* in_sizes, int n_in,
                              void* d_out, int out_size, void* d_ws, size_t ws_size,
                              hipStream_t stream) {
  (void)in_sizes; (void)n_in; (void)out_size; (void)ws_size;
  const float* x     = (const float*)d_in[0];
  const float* qenc  = (const float*)d_in[1];
  const float* Wk    = (const float*)d_in[2];
  const float* Wv    = (const float*)d_in[3];
  const float* bv    = (const float*)d_in[4];
  const float* gam   = (const float*)d_in[5];
  const float* bet   = (const float*)d_in[6];
  const float* outw  = (const float*)d_in[7];
  const float* outb  = (const float*)d_in[8];
  float* out = (float*)d_out;

  char* ws = (char*)d_ws;
  _Float16* x_h  = (_Float16*)(ws);                  // 8192x768
  _Float16* wk_h = (_Float16*)(ws + 12582912);       // 768x768
  _Float16* wv_h = (_Float16*)(ws + 13762560);       // 768x768
  _Float16* K_f  = (_Float16*)(ws + 14942208);       // frag layout, 12.6 MB
  _Float16* V_f  = (_Float16*)(ws + 27525120);       // frag layout, 12.6 MB

  cvt_kernel<<<6144, 256, 0, stream>>>(x, x_h, 1572864);
  cvt_kernel<<<576, 256, 0, stream>>>(Wk, wk_h, 147456);
  cvt_kernel<<<576, 256, 0, stream>>>(Wv, wv_h, 147456);
  // K[s,e] = x @ Wk^T  -> fragment layout
  gemm_nt_f16<1><<<384, 256, 0, stream>>>(x_h, wk_h, K_f, nullptr, 8192, 768);
  // V^T[e,s] = Wv @ x^T + bv -> fragment layout
  gemm_nt_f16<2><<<384, 256, 0, stream>>>(wv_h, x_h, V_f, bv, 768, 8192);
  attn_kernel<<<250, 512, 0, stream>>>(qenc, K_f, V_f, gam, bet, outw, outb, out);
}